// Round 5
// baseline (158.117 us; speedup 1.0000x reference)
//
#include <hip/hip_runtime.h>
#include <hip/hip_bf16.h>

#define NDIM 16
#define HDIM 128
#define BATCH 256
#define EPS_D 1e-6f

typedef float v2f __attribute__((ext_vector_type(2)));
static __device__ __forceinline__ v2f v2(float a, float b) {
  v2f r; r.x = a; r.y = b; return r;
}
static __device__ __forceinline__ v2f splat(float a) {
  v2f r; r.x = a; r.y = a; return r;
}
#define VFMA(a, b, c) __builtin_elementwise_fma((a), (b), (c))
#define VMIN(a, b) __builtin_elementwise_min((a), (b))
#define VMAX(a, b) __builtin_elementwise_max((a), (b))

// Eigen/XNNPACK fast tanh rational approximation coefficients.
#define TCLAMP 7.99881172180175781f
#define CA1 4.89352455891786e-03f
#define CA3 6.37261928875436e-04f
#define CA5 1.48572235717979e-05f
#define CA7 5.12229709037114e-08f
#define CA9 -8.60467152213735e-11f
#define CA11 2.00018790482477e-13f
#define CA13 -2.76076847742355e-16f
#define CB0 4.89352518554385e-03f
#define CB2 2.26843463243900e-03f
#define CB4 1.18534705686654e-04f
#define CB6 1.19825839466702e-06f

// ---- Kernel 1: metric = sym(MLP(points)) + eps*I, rW1 block projections,
//      and zero-init of the G accumulator.
__global__ __launch_bounds__(256) void metric_proj_kernel(
    const float* __restrict__ points,
    const float* __restrict__ mW1, const float* __restrict__ mb1,
    const float* __restrict__ mW2, const float* __restrict__ mb2,
    const float* __restrict__ rW1, const float* __restrict__ rb1,
    float* __restrict__ metric,
    float* __restrict__ A1, float* __restrict__ Mi, float* __restrict__ Mj,
    float* __restrict__ G) {
  int b = blockIdx.x;
  int t = threadIdx.x;  // 0..255
  __shared__ float p[16];
  __shared__ float mh[128];
  __shared__ float raw[256];
  __shared__ float M[256];
  G[b * 256 + t] = 0.f;
  if (t < 16) p[t] = points[b * 16 + t];
  __syncthreads();
  if (t < 128) {
    float acc = mb1[t];
#pragma unroll
    for (int k = 0; k < 16; ++k) acc = fmaf(p[k], mW1[k * 128 + t], acc);
    mh[t] = fmaxf(acc, 0.f);
  }
  __syncthreads();
  {
    float acc = mb2[t];
#pragma unroll 8
    for (int h = 0; h < 128; ++h) acc = fmaf(mh[h], mW2[h * 256 + t], acc);
    raw[t] = acc;
  }
  __syncthreads();
  {
    int i = t >> 4, j = t & 15;
    float v = 0.5f * (raw[i * 16 + j] + raw[j * 16 + i]);
    if (i == j) v += EPS_D;
    M[t] = v;
    metric[b * 256 + t] = v;
  }
  __syncthreads();
  {
    int h = t;
    float wB[16], wC[16];
#pragma unroll
    for (int c = 0; c < 16; ++c) {
      wB[c] = rW1[(16 + c) * 256 + h];
      wC[c] = rW1[(32 + c) * 256 + h];
    }
    float a = rb1[h];
#pragma unroll
    for (int r = 0; r < 16; ++r) a = fmaf(p[r], rW1[r * 256 + h], a);
    A1[b * 256 + h] = a;
#pragma unroll 2
    for (int i = 0; i < 16; ++i) {
      float mi = 0.f, mj = 0.f;
#pragma unroll
      for (int c = 0; c < 16; ++c) {
        float m = M[i * 16 + c];
        mi = fmaf(m, wB[c], mi);
        mj = fmaf(m, wC[c], mj);
      }
      Mi[(b * 16 + i) * 256 + h] = mi;
      Mj[(b * 16 + i) * 256 + h] = mj;
    }
  }
}

// ---- Kernel 2: fused christoffel MLP + ricci layer-1 relu + i-reduction ----
// Block = 4 waves (256 thr) per (b, g); wave w owns i = 4g+w. Each lane does
// 4 triples jk = l + 64m (phase 1; note k=l&15 identical across m), then 4
// hidden units h = l + 64m (phase 2). No inter-phase barrier (per-wave tiles).
// tanh via Eigen rational x*P(x^2)/Q(x^2), |x| clamped to 7.99881; the four
// Q-reciprocals per lane-step are batched through ONE v_rcp_f32.
__global__ __launch_bounds__(256, 4) void chr_kernel(
    const float* __restrict__ metric,
    const float* __restrict__ cW1, const float* __restrict__ cb1,
    const float* __restrict__ cW2, const float* __restrict__ cb2,
    const float* __restrict__ rW1,
    const float* __restrict__ A1, const float* __restrict__ Mi,
    const float* __restrict__ Mj,
    float* __restrict__ G) {
  int blk = blockIdx.x;        // b*4 + g
  int b = blk >> 2, g = blk & 3;
  int t = threadIdx.x;         // 0..255
  int w = t >> 6, l = t & 63;  // wave, lane
  int i = g * 4 + w;
  int bi = b * 16 + i;
  __shared__ float M[256];
  __shared__ float4 z[128];    // {w1_0h, w1_1h, w1_2h, b1h}
  __shared__ float w2s[128];
  __shared__ float4 ch4[256];  // 4 per-wave tiles of 256 floats
  float* chf = (float*)ch4;
  M[t] = metric[b * 256 + t];
  if (t < 128) {
    z[t] = make_float4(cW1[t], cW1[128 + t], cW1[256 + t], cb1[t]);
    w2s[t] = cW2[t];
  }
  __syncthreads();

  // ---- phase 1: triples jk = l + 64m; pairs A=(m0,m2), B=(m1,m3) ----
  {
    int j0 = l >> 4, k0 = l & 15;  // jk=l+64m -> j=j0+4m, k=k0 for all m
    v2f x0A = v2(M[i * 16 + j0], M[i * 16 + j0 + 8]);
    v2f x0B = v2(M[i * 16 + j0 + 4], M[i * 16 + j0 + 12]);
    v2f x1A = v2(M[j0 * 16 + k0], M[(j0 + 8) * 16 + k0]);
    v2f x1B = v2(M[(j0 + 4) * 16 + k0], M[(j0 + 12) * 16 + k0]);
    float x2s = M[k0 * 16 + i];
    float c2 = cb2[0];
    v2f accA = splat(c2), accB = splat(c2);
#pragma unroll 2
    for (int h = 0; h < 128; ++h) {
      float4 Q = z[h];
      float w2h = w2s[h];
      float bb = fmaf(x2s, Q.z, Q.w);
      v2f preA = VFMA(x0A, splat(Q.x), VFMA(x1A, splat(Q.y), splat(bb)));
      v2f preB = VFMA(x0B, splat(Q.x), VFMA(x1B, splat(Q.y), splat(bb)));
      v2f tA = VMAX(VMIN(preA, splat(TCLAMP)), splat(-TCLAMP));
      v2f tB = VMAX(VMIN(preB, splat(TCLAMP)), splat(-TCLAMP));
      v2f sA = tA * tA, sB = tB * tB;
      v2f pA = VFMA(sA, splat(CA13), splat(CA11));
      v2f pB = VFMA(sB, splat(CA13), splat(CA11));
      pA = VFMA(sA, pA, splat(CA9));  pB = VFMA(sB, pB, splat(CA9));
      pA = VFMA(sA, pA, splat(CA7));  pB = VFMA(sB, pB, splat(CA7));
      pA = VFMA(sA, pA, splat(CA5));  pB = VFMA(sB, pB, splat(CA5));
      pA = VFMA(sA, pA, splat(CA3));  pB = VFMA(sB, pB, splat(CA3));
      pA = VFMA(sA, pA, splat(CA1));  pB = VFMA(sB, pB, splat(CA1));
      pA = pA * tA;  pB = pB * tB;
      v2f qA = VFMA(sA, splat(CB6), splat(CB4));
      v2f qB = VFMA(sB, splat(CB6), splat(CB4));
      qA = VFMA(sA, qA, splat(CB2));  qB = VFMA(sB, qB, splat(CB2));
      qA = VFMA(sA, qA, splat(CB0));  qB = VFMA(sB, qB, splat(CB0));
      // batched reciprocal: one v_rcp for all four q's (all q >= CB0 > 0)
      v2f prod = qA * qB;                    // (q0*q1, q2*q3)
      float r = __builtin_amdgcn_rcpf(prod.x * prod.y);
      v2f u = splat(r) * v2(prod.y, prod.x); // (1/(q0q1), 1/(q2q3))
      v2f rcpA = u * qB;                     // (1/q0, 1/q2)
      v2f rcpB = u * qA;                     // (1/q1, 1/q3)
      accA = VFMA(pA * rcpA, splat(w2h), accA);
      accB = VFMA(pB * rcpB, splat(w2h), accB);
    }
    chf[w * 256 + l] = accA.x;
    chf[w * 256 + l + 64] = accB.x;
    chf[w * 256 + l + 128] = accA.y;
    chf[w * 256 + l + 192] = accB.y;
  }
  // no __syncthreads(): each wave reads only its own ch tile.

  // ---- phase 2: hidden units h = l + 64m; pairs A=(l,l+128), B=(l+64,l+192)
  {
    int h0 = l, h1 = l + 64, h2 = l + 128, h3 = l + 192;
    v2f rcA[16], rcB[16];
#pragma unroll
    for (int kk = 0; kk < 16; ++kk) {
      const float* row = rW1 + (48 + kk) * 256;
      rcA[kk] = v2(row[h0], row[h2]);
      rcB[kk] = v2(row[h1], row[h3]);
    }
    const float* A1b = A1 + b * 256;
    const float* Mib = Mi + bi * 256;
    v2f baseA = v2(A1b[h0] + Mib[h0], A1b[h2] + Mib[h2]);
    v2f baseB = v2(A1b[h1] + Mib[h1], A1b[h3] + Mib[h3]);
    v2f haccA = splat(0.f), haccB = splat(0.f);
    for (int jj = 0; jj < 16; ++jj) {
      float4 c0 = ch4[w * 64 + jj * 4 + 0];
      float4 c1 = ch4[w * 64 + jj * 4 + 1];
      float4 c2v = ch4[w * 64 + jj * 4 + 2];
      float4 c3 = ch4[w * 64 + jj * 4 + 3];
      float cc[16] = {c0.x, c0.y, c0.z, c0.w, c1.x, c1.y, c1.z, c1.w,
                      c2v.x, c2v.y, c2v.z, c2v.w, c3.x, c3.y, c3.z, c3.w};
      const float* Mjr = Mj + (b * 16 + jj) * 256;
      v2f cpA = baseA + v2(Mjr[h0], Mjr[h2]);
      v2f cpB = baseB + v2(Mjr[h1], Mjr[h3]);
#pragma unroll
      for (int kk = 0; kk < 16; ++kk) {
        cpA = VFMA(splat(cc[kk]), rcA[kk], cpA);
        cpB = VFMA(splat(cc[kk]), rcB[kk], cpB);
      }
      haccA += VMAX(cpA, splat(0.f));
      haccB += VMAX(cpB, splat(0.f));
    }
    atomicAdd(&G[b * 256 + h0], haccA.x);
    atomicAdd(&G[b * 256 + h1], haccB.x);
    atomicAdd(&G[b * 256 + h2], haccA.y);
    atomicAdd(&G[b * 256 + h3], haccB.y);
  }
}

// ---- Kernel 3: linear layer 2 on G, symmetrize, scale ----------------------
__global__ __launch_bounds__(256) void final_kernel(
    const float* __restrict__ G,
    const float* __restrict__ rW2, const float* __restrict__ rb2,
    float* __restrict__ out) {
  int b = blockIdx.x;
  int t = threadIdx.x;
  __shared__ float4 Gs[64];
  __shared__ float T[256];
  if (t < 64) Gs[t] = ((const float4*)(G + b * 256))[t];
  __syncthreads();
  float acc = 256.f * rb2[t];
#pragma unroll 4
  for (int h4 = 0; h4 < 64; ++h4) {
    float4 gg = Gs[h4];
    acc = fmaf(gg.x, rW2[(h4 * 4 + 0) * 256 + t], acc);
    acc = fmaf(gg.y, rW2[(h4 * 4 + 1) * 256 + t], acc);
    acc = fmaf(gg.z, rW2[(h4 * 4 + 2) * 256 + t], acc);
    acc = fmaf(gg.w, rW2[(h4 * 4 + 3) * 256 + t], acc);
  }
  T[t] = acc * (1.f / 256.f);
  __syncthreads();
  int k = t >> 4, lcol = t & 15;
  out[b * 256 + t] = 0.5f * (T[k * 16 + lcol] + T[lcol * 16 + k]);
}

extern "C" void kernel_launch(void* const* d_in, const int* in_sizes, int n_in,
                              void* d_out, int out_size, void* d_ws, size_t ws_size,
                              hipStream_t stream) {
  const float* points = (const float*)d_in[0];
  const float* mW1 = (const float*)d_in[1];
  const float* mb1 = (const float*)d_in[2];
  const float* mW2 = (const float*)d_in[3];
  const float* mb2 = (const float*)d_in[4];
  const float* cW1 = (const float*)d_in[5];
  const float* cb1 = (const float*)d_in[6];
  const float* cW2 = (const float*)d_in[7];
  const float* cb2 = (const float*)d_in[8];
  const float* rW1 = (const float*)d_in[9];
  const float* rb1 = (const float*)d_in[10];
  const float* rW2 = (const float*)d_in[11];
  const float* rb2 = (const float*)d_in[12];
  float* out = (float*)d_out;

  float* ws = (float*)d_ws;
  float* metric = ws;                 // 65536
  float* A1 = metric + 65536;         // 65536
  float* Mi = A1 + 65536;             // 1048576
  float* Mj = Mi + 1048576;           // 1048576
  float* G = Mj + 1048576;            // 65536

  metric_proj_kernel<<<BATCH, 256, 0, stream>>>(points, mW1, mb1, mW2, mb2,
                                                rW1, rb1, metric, A1, Mi, Mj, G);
  chr_kernel<<<BATCH * 4, 256, 0, stream>>>(metric, cW1, cb1, cW2, cb2, rW1,
                                            A1, Mi, Mj, G);
  final_kernel<<<BATCH, 256, 0, stream>>>(G, rW2, rb2, out);
}